// Round 2
// 202.309 us; speedup vs baseline: 1.0016x; 1.0016x over previous
//
#include <hip/hip_runtime.h>
#include <stdint.h>

// SE block, float32: out = x * sigmoid(MLP(mean_hw(x)))
// x[32,256,56,56]; B=32, CH=256, BOT=32, HW=56*56=3136
#define BATCH 32
#define CH    256
#define BOT   32
#define HW    3136
#define CPP   784                 // float4 chunks per plane (HW/4)

// ---------------- Kernel A: global average pool (verified round-0 code) ----
// One wave per (b,c) plane; block = 4 waves = 4 planes. grid = 2048.
__global__ __launch_bounds__(256) void pool_kernel(
        const float* __restrict__ x, float* __restrict__ s_out) {
    const int wave = threadIdx.x >> 6;
    const int lane = threadIdx.x & 63;
    const int bc = blockIdx.x * 4 + wave;   // < 8192

    const float4* p4 = (const float4*)(x + (size_t)bc * HW);
    float sum = 0.f;
    #pragma unroll
    for (int i = 0; i < 13; ++i) {          // 13*64 = 832 >= 784
        int idx = lane + i * 64;
        if (idx < CPP) {
            float4 v = p4[idx];
            sum += (v.x + v.y) + (v.z + v.w);
        }
    }
    #pragma unroll
    for (int off = 32; off > 0; off >>= 1)
        sum += __shfl_down(sum, off, 64);
    if (lane == 0) s_out[bc] = sum * (1.0f / (float)HW);
}

// ---------------- Kernel B: fused MLP + scale ------------------------------
// grid = 2048, block = 256. Each block: 4 planes (one wave each), all in one
// batch row (4 | 256 so b = blockIdx.x>>6 is block-uniform). The block
// redundantly computes the row MLP (s-row 1KB + w1 32KB, L2-broadcast),
// then each wave gates + scales its plane. x re-read hits L3 (resident
// from kernel A); only the out write goes to HBM.
__global__ __launch_bounds__(256) void mlp_scale_kernel(
        const float* __restrict__ x, const float* __restrict__ s,
        const float* __restrict__ w1, const float* __restrict__ b1,
        const float* __restrict__ w2, const float* __restrict__ b2,
        float* __restrict__ out) {
    __shared__ float s_lds[CH];
    __shared__ float hs[BOT];
    const int t    = threadIdx.x;
    const int wave = t >> 6;
    const int lane = t & 63;
    const int bc   = blockIdx.x * 4 + wave;   // plane id < 8192
    const int b    = blockIdx.x >> 6;         // batch row (uniform per block)

    s_lds[t] = s[b * CH + t];
    __syncthreads();

    // h[o] = relu(b1[o] + dot(s[b,:], w1[o,:])); 8 lanes per output
    {
        const int o = t >> 3;
        const int part = t & 7;
        const float4* w4 = (const float4*)(w1 + o * CH + part * 32);
        const float4* s4 = (const float4*)(s_lds + part * 32);
        float acc = 0.f;
        #pragma unroll
        for (int j = 0; j < 8; ++j) {
            float4 wv = w4[j];
            float4 sv = s4[j];
            acc = fmaf(sv.x, wv.x, acc);
            acc = fmaf(sv.y, wv.y, acc);
            acc = fmaf(sv.z, wv.z, acc);
            acc = fmaf(sv.w, wv.w, acc);
        }
        acc += __shfl_xor(acc, 1, 64);
        acc += __shfl_xor(acc, 2, 64);
        acc += __shfl_xor(acc, 4, 64);
        if (part == 0) hs[o] = fmaxf(acc + b1[o], 0.f);
    }
    __syncthreads();

    // gate for this wave's channel (all 64 lanes redundantly, same FMA order
    // as the verified round-0 mlp kernel -> bitwise identical g)
    const int c = bc & (CH - 1);
    const float4* wg = (const float4*)(w2 + c * BOT);
    float acc = b2[c];
    #pragma unroll
    for (int j = 0; j < 8; ++j) {
        float4 wv = wg[j];
        acc = fmaf(hs[j * 4 + 0], wv.x, acc);
        acc = fmaf(hs[j * 4 + 1], wv.y, acc);
        acc = fmaf(hs[j * 4 + 2], wv.z, acc);
        acc = fmaf(hs[j * 4 + 3], wv.w, acc);
    }
    const float gv = 1.0f / (1.0f + __expf(-acc));

    // scale this wave's plane
    const float4* p4 = (const float4*)(x + (size_t)bc * HW);
    float4* o4 = (float4*)(out + (size_t)bc * HW);
    #pragma unroll
    for (int i = 0; i < 13; ++i) {
        int idx = lane + i * 64;
        if (idx < CPP) {
            float4 v = p4[idx];
            v.x *= gv; v.y *= gv; v.z *= gv; v.w *= gv;
            o4[idx] = v;
        }
    }
}

extern "C" void kernel_launch(void* const* d_in, const int* in_sizes, int n_in,
                              void* d_out, int out_size, void* d_ws, size_t ws_size,
                              hipStream_t stream) {
    const float* x  = (const float*)d_in[0];
    const float* w1 = (const float*)d_in[1];
    const float* b1 = (const float*)d_in[2];
    const float* w2 = (const float*)d_in[3];
    const float* b2 = (const float*)d_in[4];
    float* out = (float*)d_out;
    float* s   = (float*)d_ws;               // 8192 floats

    pool_kernel     <<<BATCH * CH / 4, 256, 0, stream>>>(x, s);
    mlp_scale_kernel<<<BATCH * CH / 4, 256, 0, stream>>>(x, s, w1, b1, w2, b2, out);
}